// Round 14
// baseline (969.251 us; speedup 1.0000x reference)
//
#include <hip/hip_runtime.h>

typedef unsigned short u16;
typedef unsigned int u32;
typedef unsigned long long u64;

#define N_USERS 100000
#define N_ITEMS 200000
#define N_NODES 300000
#define D 64
#define HYP 128
#define NNZ 4000000

// out is 96M fp32 elems: [user_out|item_out|gcn_hidden(2)|hgnn_hidden(2)]
constexpr long long SZL      = 19200000LL;        // one 300000x64 tensor
constexpr long long OUT_GCN0 = SZL;               // gcn_hidden base
constexpr long long OUT_HG0  = 3*SZL;             // hgnn_hidden base
// CSR {col,val} pairs overlaid on hgnn[l=1] region [4*SZL,5*SZL): last read by
// layer-1 spmm; hgnn[1] written only by the final fused GEMM after that.
constexpr long long OUT_PAIR = 4*SZL;
// step3 partial tiles (587 x 8192 floats = 19.2MB) after pair_s, same region.
constexpr long long OUT_PART = OUT_PAIR + 8000000LL;
// bin (bucketed edges, NNZ int2 = 32MB) overlaid on gcn_hidden[l=1] region
// [2*SZL,3*SZL): consumed by k_bfin, long before layer-1 spmm writes gcn[1].
constexpr long long OUT_BIN  = 2*SZL;

// ---- bucketed CSR build geometry ----
#define BSHIFT 10
#define RPB 1024                                   // rows per bucket
constexpr int NBKT = (N_NODES + RPB - 1)/RPB;      // 293 buckets
#define EPB 8192                                   // edges per stage-1 block
constexpr int NB_H = (NNZ + EPB - 1)/EPB;          // 489 stage-1 blocks

#define S3_CHUNK 512
constexpr int NB_S3U = (N_USERS + S3_CHUNK - 1)/S3_CHUNK;  // 196
constexpr int NB_S3I = (N_ITEMS + S3_CHUNK - 1)/S3_CHUNK;  // 391
constexpr int NB_S3  = NB_S3U + NB_S3I;                    // 587
constexpr int UB64   = N_USERS/32;                         // 3125 user gemm blocks
constexpr int NB_GEMM= N_NODES/32;                         // 9375
constexpr int NB_SPMM= N_NODES/4;                          // 75000
constexpr int NB_RED = 64;                                 // reduce blocks (32 user + 32 item)

typedef __attribute__((ext_vector_type(8))) short short8;
typedef __attribute__((ext_vector_type(4))) float f32x4;

__device__ __forceinline__ float bf2f(u16 u){ u32 i = ((u32)u) << 16; return __builtin_bit_cast(float, i); }
__device__ __forceinline__ u16 f2bf(float f){
  u32 i = __builtin_bit_cast(u32, f);
  return (u16)((i + 0x7FFFu + ((i >> 16) & 1u)) >> 16);
}

// ---------------- GEMM body ---------------------------------------------------
// C[M x N] = A[M x K] @ B[K x N]; A row-major bf16 (AF32=false) or fp32
// converted on the fly with the same f2bf rounding (AF32=true, bit-identical).
// B fp32 staged in LDS as bf16. 32 rows/block, 4 waves. User+item merged.
// FUSE: layer epilogue h = gcn+hg; hsum += h; hbf = bf16(h); hg nontemporal.
// WRINIT (requires AF32): the (wave&1)==0 waves also emit hsum=f32(A) and
// hbf=bf16(A) while staging A -- folds the old k_init into this GEMM (each
// (row,elem) is staged by exactly one such lane), saving a second 115MB read
// of emb.
template<int K, int N, bool C32, bool FUSE, bool AF32, bool WRINIT>
__device__ __forceinline__ void gemm_body(int bid, const void* __restrict__ A0,
                                          const float* __restrict__ Bu,
                                          const float* __restrict__ Bi,
                                          void* __restrict__ Cv,
                                          const float* __restrict__ gcn0,
                                          float* __restrict__ hsum0,
                                          u16* __restrict__ hbf0,
                                          int ublocks, u32* blds){
  bool it = bid >= ublocks;
  int blk = it ? bid - ublocks : bid;
  const float* B = it ? Bi : Bu;
  size_t aoff = it ? (size_t)ublocks*32*K : 0;
  size_t co   = it ? (size_t)ublocks*32*N : 0;

  constexpr int SROW = N + 2;                 // padded u16 stride (odd dword stride)
  constexpr int PAIRS = K*N/2;
  for (int p = threadIdx.x; p < PAIRS; p += 256){
    int k = p/(N/2), c2 = p%(N/2);
    float f0 = B[2*p], f1 = B[2*p+1];
    blds[k*(SROW/2) + c2] = (u32)f2bf(f0) | ((u32)f2bf(f1)<<16);
  }
  __syncthreads();
  const u16* bl = (const u16*)blds;
  int wave = threadIdx.x>>6, lane = threadIdx.x&63, q = lane>>4, lm = lane&15;
  constexpr int NT = N/32;
  int mt = wave>>1, ntb = (wave&1)*NT;
  int r0 = blk*32;
  f32x4 acc[NT];
  #pragma unroll
  for (int nt=0; nt<NT; ++nt) acc[nt] = (f32x4){0.f,0.f,0.f,0.f};
  size_t arow = aoff + (size_t)(r0 + mt*16 + lm)*K + q*8;
  #pragma unroll
  for (int ks = 0; ks < K/32; ++ks){
    short8 a;
    if (AF32){
      const float* af = (const float*)A0 + arow + ks*32;
      float4 f0 = *(const float4*)af;
      float4 f1 = *(const float4*)(af + 4);
      a[0]=(short)f2bf(f0.x); a[1]=(short)f2bf(f0.y);
      a[2]=(short)f2bf(f0.z); a[3]=(short)f2bf(f0.w);
      a[4]=(short)f2bf(f1.x); a[5]=(short)f2bf(f1.y);
      a[6]=(short)f2bf(f1.z); a[7]=(short)f2bf(f1.w);
      if (WRINIT && (wave & 1) == 0){
        // fold k_init: hsum = emb (fp32), h_bf = bf16(emb). Each (row,elem)
        // staged by exactly one lane of waves 0/2 (mt covers rows, q+ks elems).
        *(float4*)(hsum0 + arow + ks*32)     = f0;
        *(float4*)(hsum0 + arow + ks*32 + 4) = f1;
        *(short8*)(hbf0 + arow + ks*32)      = a;
      }
    } else {
      a = *(const short8*)((const u16*)A0 + arow + ks*32);
    }
    #pragma unroll
    for (int nt = 0; nt < NT; ++nt){
      short8 b;
      #pragma unroll
      for (int j = 0; j < 8; ++j)
        b[j] = (short)bl[(ks*32 + q*8 + j)*SROW + (ntb+nt)*16 + lm];
      acc[nt] = __builtin_amdgcn_mfma_f32_16x16x32_bf16(a, b, acc[nt], 0, 0, 0);
    }
  }
  #pragma unroll
  for (int nt = 0; nt < NT; ++nt)
    #pragma unroll
    for (int r = 0; r < 4; ++r){
      int row = r0 + mt*16 + q*4 + r;       // C/D: col=lane&15, row=quad*4+reg (m89)
      int col = (ntb+nt)*16 + lm;
      size_t idx = co + (size_t)row*N + col;
      if (C32){
        float hg = acc[nt][r];
        if (FUSE){
          __builtin_nontemporal_store(hg, &((float*)Cv)[idx]);  // hg: streaming
          float hv = gcn0[idx] + hg;
          hsum0[idx] += hv;
          hbf0[idx] = f2bf(hv);
        } else {
          ((float*)Cv)[idx] = hg;
        }
      } else {
        ((u16*)Cv)[idx] = f2bf(acc[nt][r]);
      }
    }
}

template<int K, int N, bool C32, bool FUSE>
__global__ __launch_bounds__(256) void k_gemm_tall(const u16* __restrict__ A0,
                                                   const float* __restrict__ Bu,
                                                   const float* __restrict__ Bi,
                                                   void* __restrict__ Cv,
                                                   const float* __restrict__ gcn0,
                                                   float* __restrict__ hsum0,
                                                   u16* __restrict__ hbf0,
                                                   int ublocks){
  __shared__ u32 blds[K*(N+2)/2];
  gemm_body<K,N,C32,FUSE,false,false>((int)blockIdx.x, A0, Bu, Bi, Cv, gcn0, hsum0, hbf0, ublocks, blds);
}

// k_front: bucket-histogram (LDS atomics only) || hyper GEMM (emb fp32 direct,
// WRINIT emits h_bf/hsum from the A-staging -- the old init blocks are gone).
__global__ __launch_bounds__(256) void k_front(const float* __restrict__ ue,
                                               const float* __restrict__ ie,
                                               u16* __restrict__ h_bf,
                                               float* __restrict__ hsum,
                                               const int* __restrict__ rows_,
                                               int* __restrict__ cnt_bb,
                                               const float* __restrict__ user_w,
                                               const float* __restrict__ item_w,
                                               u16* __restrict__ hyper){
  __shared__ u32 shmem[64*(HYP+2)/2];     // 16.6KB; bucket hist aliases first 293 ints
  int bid = blockIdx.x;
  int tid = threadIdx.x;
  if (bid < NB_H){
    int* hist = (int*)shmem;
    for (int i = tid; i < NBKT; i += 256) hist[i] = 0;
    __syncthreads();
    #pragma unroll
    for (int it = 0; it < 8; ++it){
      int e4 = bid*EPB + it*1024 + tid*4;
      if (e4 < NNZ){
        int4 r4 = *(const int4*)(rows_ + e4);
        atomicAdd(&hist[min(max(r4.x,0),N_NODES-1)>>BSHIFT], 1);
        atomicAdd(&hist[min(max(r4.y,0),N_NODES-1)>>BSHIFT], 1);
        atomicAdd(&hist[min(max(r4.z,0),N_NODES-1)>>BSHIFT], 1);
        atomicAdd(&hist[min(max(r4.w,0),N_NODES-1)>>BSHIFT], 1);
      }
    }
    __syncthreads();
    for (int i = tid; i < NBKT; i += 256) cnt_bb[i*NB_H + bid] = hist[i];
    return;
  }
  int gb = bid - NB_H;
  const void* A0 = (gb < UB64) ? (const void*)ue
                               : (const void*)(ie - (size_t)UB64*32*64);
  gemm_body<64,HYP,false,false,true,true>(gb, A0, user_w, item_w, hyper,
                                          nullptr, hsum, h_bf, UB64, shmem);
}

// Per-bucket exclusive scan of cnt_bb over the 489 stage-1 blocks.
__global__ __launch_bounds__(256) void k_bscan2(int* __restrict__ cnt_bb,
                                                int* __restrict__ btot){
  __shared__ int sO[512], sA[512], sB[512];
  int b = blockIdx.x, tid = threadIdx.x;
  for (int i = tid; i < 512; i += 256){
    int v = (i < NB_H) ? cnt_bb[b*NB_H + i] : 0;
    sO[i] = v; sA[i] = v;
  }
  __syncthreads();
  int* cur = sA; int* nxt = sB;
  for (int off = 1; off < 512; off <<= 1){
    for (int i = tid; i < 512; i += 256)
      nxt[i] = cur[i] + ((i >= off) ? cur[i-off] : 0);
    __syncthreads();
    int* t = cur; cur = nxt; nxt = t;
  }
  for (int i = tid; i < NB_H; i += 256)
    cnt_bb[b*NB_H + i] = cur[i] - sO[i];    // exclusive
  if (tid == 0) btot[b] = cur[NB_H-1];
}

// ---------------- step3: partial tiles (no hot atomics) ----------------------
__device__ __forceinline__ void step3_body(const u16* __restrict__ Hy,
                                           const u16* __restrict__ Hm,
                                           float* __restrict__ outp, int rows, int k0,
                                           u32* __restrict__ lds){
  u32* hyl = lds;            // 32 k-rows x 128 elems, stride 130 u16 (65 u32)
  u32* hml = lds + 32*65;    // 32 k-rows x 64 elems,  stride 66 u16 (33 u32)
  const u16* hyl16 = (const u16*)hyl;
  const u16* hml16 = (const u16*)hml;
  int tid = threadIdx.x;
  int wave = tid>>6, lane = tid&63, q = lane>>4, lm = lane&15;
  f32x4 acc[2][4];
  #pragma unroll
  for (int i=0;i<2;i++)
    #pragma unroll
    for (int j=0;j<4;j++) acc[i][j] = (f32x4){0.f,0.f,0.f,0.f};
  for (int kk=0; kk<S3_CHUNK/32; ++kk){
    int kb = k0 + kk*32;
    #pragma unroll
    for (int d0=0; d0<8; ++d0){
      int d = d0*256 + tid;
      int kr = d>>6, c2 = d&63, g = kb+kr;
      hyl[kr*65 + c2] = (g < rows) ? ((const u32*)Hy)[(size_t)g*64 + c2] : 0u;
    }
    #pragma unroll
    for (int d0=0; d0<4; ++d0){
      int d = d0*256 + tid;
      int kr = d>>5, c2 = d&31, g = kb+kr;
      hml[kr*33 + c2] = (g < rows) ? ((const u32*)Hm)[(size_t)g*32 + c2] : 0u;
    }
    __syncthreads();
    short8 a[2], b[4];
    #pragma unroll
    for (int ml=0; ml<2; ++ml)
      #pragma unroll
      for (int j=0;j<8;j++)
        a[ml][j] = (short)hyl16[(q*8+j)*130 + (wave*2+ml)*16 + lm];  // A[m][k]=Hy[k][m]
    #pragma unroll
    for (int nt=0; nt<4; ++nt)
      #pragma unroll
      for (int j=0;j<8;j++)
        b[nt][j] = (short)hml16[(q*8+j)*66 + nt*16 + lm];            // B[k][n]=Hm[k][n]
    #pragma unroll
    for (int ml=0; ml<2; ++ml)
      #pragma unroll
      for (int nt=0; nt<4; ++nt)
        acc[ml][nt] = __builtin_amdgcn_mfma_f32_16x16x32_bf16(a[ml], b[nt], acc[ml][nt], 0,0,0);
    __syncthreads();
  }
  #pragma unroll
  for (int ml=0; ml<2; ++ml)
    #pragma unroll
    for (int nt=0; nt<4; ++nt)
      #pragma unroll
      for (int r=0;r<4;r++){
        int m = (wave*2+ml)*16 + q*4 + r;
        int n = nt*16 + lm;
        __builtin_nontemporal_store(acc[ml][nt][r], &outp[m*64 + n]);
      }
}

__device__ __forceinline__ void step3_dispatch(int bid, const u16* __restrict__ hyper,
                                               const u16* __restrict__ h,
                                               float* __restrict__ part, u32* lds){
  float* outp = part + (size_t)bid*8192;
  if (bid < NB_S3U)
    step3_body(hyper, h, outp, N_USERS, bid*S3_CHUNK, lds);
  else
    step3_body(hyper + (size_t)N_USERS*HYP, h + (size_t)N_USERS*D,
               outp, N_ITEMS, (bid - NB_S3U)*S3_CHUNK, lds);
}

__global__ __launch_bounds__(256) void k_step3(const u16* __restrict__ hyper,
                                               const u16* __restrict__ h,
                                               float* __restrict__ part){
  __shared__ u32 lds[32*65 + 32*33];
  step3_dispatch((int)blockIdx.x, hyper, h, part, lds);
}

// k_mid: bbin (LDS-cursor bucket scatter) || step3 layer 0 (MFMA).
// bin stores are PLAIN: each block exclusively owns ~224B runs per bucket ->
// L2 write-allocate merges ~8 edges/line (nt here caused 4x amplification, r8).
// Bucket offsets re-derived from btot via a 512-wide LDS scan (k_bbase folded).
__global__ __launch_bounds__(256) void k_mid(const int* __restrict__ rows_,
                                             const int* __restrict__ cols_,
                                             const float* __restrict__ vals_,
                                             const int* __restrict__ cnt_bb,
                                             const int* __restrict__ btot,
                                             int2* __restrict__ bin,
                                             const u16* __restrict__ hyper,
                                             const u16* __restrict__ h_bf,
                                             float* __restrict__ part){
  __shared__ u32 lds[32*65 + 32*33];      // 12.5KB; bbin state aliases the front
  int bid = blockIdx.x, tid = threadIdx.x;
  if (bid < NB_H){
    int* cur = (int*)lds;                 // [0,293): cursors
    int* scA = (int*)lds + 512;           // [512,1024): scan buf A
    int* scB = (int*)lds + 1024;          // [1024,1536): scan buf B
    for (int i = tid; i < 512; i += 256) scA[i] = (i < NBKT) ? btot[i] : 0;
    __syncthreads();
    int* c = scA; int* n = scB;
    for (int off = 1; off < 512; off <<= 1){
      for (int i = tid; i < 512; i += 256)
        n[i] = c[i] + ((i >= off) ? c[i-off] : 0);
      __syncthreads();
      int* t = c; c = n; n = t;
    }
    for (int i = tid; i < NBKT; i += 256)
      cur[i] = ((i == 0) ? 0 : c[i-1]) + cnt_bb[i*NB_H + bid];
    __syncthreads();
    #pragma unroll
    for (int it = 0; it < 8; ++it){
      int e4 = bid*EPB + it*1024 + tid*4;
      if (e4 < NNZ){
        int4 r4 = *(const int4*)(rows_ + e4);
        int4 c4 = *(const int4*)(cols_ + e4);
        float4 v4 = *(const float4*)(vals_ + e4);
        int rr[4] = {r4.x, r4.y, r4.z, r4.w};
        int cc[4] = {c4.x, c4.y, c4.z, c4.w};
        float vv[4] = {v4.x, v4.y, v4.z, v4.w};
        #pragma unroll
        for (int j = 0; j < 4; ++j){
          int r = min(max(rr[j],0), N_NODES-1);
          int cl = min(max(cc[j],0), N_NODES-1);
          int pos = atomicAdd(&cur[r >> BSHIFT], 1);
          pos = min(max(pos,0), NNZ-1);
          int pack = ((r & (RPB-1)) << 19) | cl;  // rowlocal:10b | col:19b
          bin[pos] = make_int2(pack, __float_as_int(vv[j]));  // plain: let L2 merge
        }
      }
    }
    return;
  }
  step3_dispatch(bid - NB_H, hyper, h_bf, part, lds);
}

// Finalize: per bucket, LDS row-histogram -> LDS scan -> write rowptr ->
// LDS-cursor scatter of {col,val} into the bucket's L2-resident output range.
// bin is read-once: nontemporal loads. Bucket offsets from btot scan (k_bbase
// folded): ebeg = incl[b-1], eend = incl[b].
__global__ __launch_bounds__(256) void k_bfin(const int2* __restrict__ bin,
                                              const int* __restrict__ btot,
                                              int* __restrict__ rowptr,
                                              int2* __restrict__ pair_s){
  __shared__ int s_hist[RPB];
  __shared__ int sA[RPB], sB[RPB];
  int b = blockIdx.x, tid = threadIdx.x;
  // btot scan (512-wide) using sA/sB before their row-scan use
  for (int i = tid; i < 512; i += 256) sA[i] = (i < NBKT) ? btot[i] : 0;
  __syncthreads();
  int* cur = sA; int* nxt = sB;
  for (int off = 1; off < 512; off <<= 1){
    for (int i = tid; i < 512; i += 256)
      nxt[i] = cur[i] + ((i >= off) ? cur[i-off] : 0);
    __syncthreads();
    int* t = cur; cur = nxt; nxt = t;
  }
  int ebeg = (b == 0) ? 0 : cur[b-1];
  int eend = cur[b];
  int base = ebeg;
  __syncthreads();
  for (int i = tid; i < RPB; i += 256) s_hist[i] = 0;
  __syncthreads();
  for (int e = ebeg + tid; e < eend; e += 256){
    u64 pvu = __builtin_nontemporal_load((const u64*)(bin + e));
    int pack = (int)(u32)pvu;
    atomicAdd(&s_hist[(pack >> 19) & (RPB-1)], 1);
  }
  __syncthreads();
  for (int i = tid; i < RPB; i += 256) sA[i] = s_hist[i];
  __syncthreads();
  cur = sA; nxt = sB;
  for (int off = 1; off < RPB; off <<= 1){
    for (int i = tid; i < RPB; i += 256)
      nxt[i] = cur[i] + ((i >= off) ? cur[i-off] : 0);
    __syncthreads();
    int* t = cur; cur = nxt; nxt = t;
  }
  // cur = inclusive; cursor/rowptr value = base + (inclusive - hist) = exclusive
  int r0 = b << BSHIFT;
  for (int i = tid; i < RPB; i += 256){
    int v = base + cur[i] - s_hist[i];
    nxt[i] = v;                          // nxt reused as the scatter cursor
    if (r0 + i <= N_NODES) rowptr[r0 + i] = v;
  }
  __syncthreads();
  for (int e = ebeg + tid; e < eend; e += 256){
    u64 pvu = __builtin_nontemporal_load((const u64*)(bin + e));
    int pack = (int)(u32)pvu;
    int rl = (pack >> 19) & (RPB-1);
    int c  = pack & 0x7FFFF;
    int pos = atomicAdd(&nxt[rl], 1);
    pos = min(max(pos,0), NNZ-1);
    pair_s[pos] = make_int2(c, (int)(u32)(pvu >> 32));
  }
}

// ---------------- spmm (+merged partial-tile reduce) --------------------------
// Blocks [0,NB_RED): full-range sum of step3 partials -> tmp (plain stores, no
// atomics, no pre-zero). Blocks [NB_RED,...): one wave per row. OCT-EDGE u128
// gathers: lane = g*8+lp, g in [0,8) = edge subgroup, lp in [0,8) = elem octet.
// Each lane loads uint4 (16B = 8 bf16) at h[ce]*128B + lp*16B; 8 lanes cover
// one edge's row; 8 gather instructions cover ALL 64 edges of a batch (inner
// edge-loop eliminated; was 8 x ceil(deg/16)). 4x fewer shuffles. Padded slots
// (c=0,v=0) gather the cached row 0 and contribute 0. Epilogue: shfl_xor
// (8/16/32) reduce across g; lanes 0-7 store 2 x f32x4 (256B/row, nt).
__global__ __launch_bounds__(256) void k_spmm(const int* __restrict__ rp,
                                              const int2* __restrict__ ps,
                                              const u16* __restrict__ h,
                                              float* __restrict__ gout,
                                              const float* __restrict__ part,
                                              float* __restrict__ tmp){
  int bid = blockIdx.x;
  if (bid < NB_RED){
    int j = (bid & 31)*256 + threadIdx.x;
    float s = 0.f;
    if (bid < 32){
      for (int b = 0; b < NB_S3U; ++b) s += part[(size_t)b*8192 + j];
      tmp[j] = s;
    } else {
      for (int b = NB_S3U; b < NB_S3; ++b) s += part[(size_t)b*8192 + j];
      tmp[HYP*D + j] = s;
    }
    return;
  }
  int r = (bid - NB_RED)*4 + (threadIdx.x>>6);
  int lane = threadIdx.x & 63;
  int g  = lane >> 3;            // edge subgroup (8 edges per gather round)
  int lp = lane & 7;             // elem-octet index within the row
  int beg = rp[r], end = rp[r+1];
  float a0=0.f,a1=0.f,a2=0.f,a3=0.f,a4=0.f,a5=0.f,a6=0.f,a7=0.f;
  for (int base = beg; base < end; base += 64){
    int c = 0; float v = 0.f;
    if (base + lane < end){
      u64 pvu = __builtin_nontemporal_load((const u64*)(ps + base + lane));
      c = (int)(u32)pvu; v = __int_as_float((int)(u32)(pvu >> 32));
    }
    int ce[8]; float ve[8]; uint4 hw[8];
    #pragma unroll
    for (int j = 0; j < 8; ++j){
      ce[j] = __shfl(c, 8*j + g);
      ve[j] = __shfl(v, 8*j + g);
    }
    #pragma unroll
    for (int j = 0; j < 8; ++j)
      hw[j] = *(const uint4*)(h + (size_t)ce[j]*64 + lp*8);  // 8 gathers x 8 edges
    #pragma unroll
    for (int j = 0; j < 8; ++j){
      a0 += ve[j] * bf2f((u16)(hw[j].x & 0xFFFFu));
      a1 += ve[j] * bf2f((u16)(hw[j].x >> 16));
      a2 += ve[j] * bf2f((u16)(hw[j].y & 0xFFFFu));
      a3 += ve[j] * bf2f((u16)(hw[j].y >> 16));
      a4 += ve[j] * bf2f((u16)(hw[j].z & 0xFFFFu));
      a5 += ve[j] * bf2f((u16)(hw[j].z >> 16));
      a6 += ve[j] * bf2f((u16)(hw[j].w & 0xFFFFu));
      a7 += ve[j] * bf2f((u16)(hw[j].w >> 16));
    }
  }
  #pragma unroll
  for (int m = 8; m <= 32; m <<= 1){
    a0 += __shfl_xor(a0, m); a1 += __shfl_xor(a1, m);
    a2 += __shfl_xor(a2, m); a3 += __shfl_xor(a3, m);
    a4 += __shfl_xor(a4, m); a5 += __shfl_xor(a5, m);
    a6 += __shfl_xor(a6, m); a7 += __shfl_xor(a7, m);
  }
  if (g == 0){
    float* dst = gout + (size_t)r*64 + lp*8;
    f32x4 w0 = {a0,a1,a2,a3};
    f32x4 w1 = {a4,a5,a6,a7};
    __builtin_nontemporal_store(w0, (f32x4*)dst);        // ext-vector: nt-legal
    __builtin_nontemporal_store(w1, (f32x4*)(dst + 4));
  }
}

extern "C" void kernel_launch(void* const* d_in, const int* in_sizes, int n_in,
                              void* d_out, int out_size, void* d_ws, size_t ws_size,
                              hipStream_t stream) {
  const float* user_emb = (const float*)d_in[0];
  const float* item_emb = (const float*)d_in[1];
  const float* user_w   = (const float*)d_in[2];
  const float* item_w   = (const float*)d_in[3];
  const float* adj_vals = (const float*)d_in[4];
  const int* adj_rows = (const int*)d_in[5];
  const int* adj_cols = (const int*)d_in[6];
  float* out = (float*)d_out;

  // ws (~117 MB): hyper 76.8M + h_bf 38.4M + rowptr 1.2M + cnt_bb 0.6M + misc
  char* w = (char*)d_ws;
  auto alloc = [&](size_t b){ void* p = (void*)w; w += (b + 255) & ~(size_t)255; return p; };
  u16*   hyper  = (u16*)  alloc((size_t)N_NODES*HYP*2);
  u16*   h_bf   = (u16*)  alloc((size_t)N_NODES*D*2);
  int*   rowptr = (int*)  alloc((size_t)(N_NODES+1)*4);
  int*   cnt_bb = (int*)  alloc((size_t)NBKT*NB_H*4);
  int*   btot   = (int*)  alloc((size_t)NBKT*4);
  float* tmp_u  = (float*)alloc((size_t)HYP*D*4);  // tmp_i = tmp_u + HYP*D
  float* tmp_i  = (float*)alloc((size_t)HYP*D*4);
  (void)tmp_i;

  // Overlays on out (regions free until noted launch):
  int2*  pair_s = (int2*)(out + OUT_PAIR);         // hgnn[1]: free until gemm1
  float* part   = out + OUT_PART;                  // after pair_s, same region
  int2*  bin    = (int2*)(out + OUT_BIN);          // gcn[1]: free until l1 spmm
  float* hsum   = out;                             // fp32 hidden-sum accumulator

  // 1. bucket-hist (LDS atomics) || hyper-GEMM (emb fp32 direct, WRINIT emits
  //    h_bf + hsum from the A-staging; the old init pass is deleted)
  k_front<<<NB_H + NB_GEMM, 256, 0, stream>>>(
      user_emb, item_emb, h_bf, hsum, adj_rows, cnt_bb, user_w, item_w, hyper);

  // 2. scan block-bucket matrix (bucket offsets derived in consumers)
  k_bscan2<<<NBKT, 256, 0, stream>>>(cnt_bb, btot);

  // 3. bin edges by bucket || step3 layer 0
  k_mid<<<NB_H + NB_S3, 256, 0, stream>>>(adj_rows, adj_cols, adj_vals,
                                          cnt_bb, btot, bin, hyper, h_bf, part);

  // 4. finalize CSR (rowptr + row-sorted pairs, L2-resident per-bucket scatter)
  k_bfin<<<NBKT, 256, 0, stream>>>(bin, btot, rowptr, pair_s);

  // 5. layer-0 spmm || reduce(l0 partials -> tmp)
  k_spmm<<<NB_RED + NB_SPMM, 256, 0, stream>>>(rowptr, pair_s, h_bf,
                                               out + OUT_GCN0, part, tmp_u);
  // 6. layer-0 fused hg GEMM + epilogue
  k_gemm_tall<128,64,true,true><<<NB_GEMM, 256, 0, stream>>>(
      hyper, tmp_u, tmp_u + HYP*D, out + OUT_HG0, out + OUT_GCN0, hsum, h_bf, UB64);

  // 7. step3 layer 1 (h_bf updated by gemm0)
  k_step3<<<NB_S3, 256, 0, stream>>>(hyper, h_bf, part);
  // 8. layer-1 spmm || reduce
  k_spmm<<<NB_RED + NB_SPMM, 256, 0, stream>>>(rowptr, pair_s, h_bf,
                                               out + OUT_GCN0 + SZL, part, tmp_u);
  // 9. layer-1 fused hg GEMM + epilogue
  k_gemm_tall<128,64,true,true><<<NB_GEMM, 256, 0, stream>>>(
      hyper, tmp_u, tmp_u + HYP*D, out + OUT_HG0 + SZL, out + OUT_GCN0 + SZL,
      hsum, h_bf, UB64);
}

// Round 15
// 863.558 us; speedup vs baseline: 1.1224x; 1.1224x over previous
//
#include <hip/hip_runtime.h>

typedef unsigned short u16;
typedef unsigned int u32;
typedef unsigned long long u64;

#define N_USERS 100000
#define N_ITEMS 200000
#define N_NODES 300000
#define D 64
#define HYP 128
#define NNZ 4000000

// out is 96M fp32 elems: [user_out|item_out|gcn_hidden(2)|hgnn_hidden(2)]
constexpr long long SZL      = 19200000LL;        // one 300000x64 tensor
constexpr long long OUT_GCN0 = SZL;               // gcn_hidden base
constexpr long long OUT_HG0  = 3*SZL;             // hgnn_hidden base
// CSR {col,val} pairs overlaid on hgnn[l=1] region [4*SZL,5*SZL): last read by
// layer-1 spmm; hgnn[1] written only by the final fused GEMM after that.
constexpr long long OUT_PAIR = 4*SZL;
// step3 partial tiles (587 x 8192 floats = 19.2MB) after pair_s, same region.
constexpr long long OUT_PART = OUT_PAIR + 8000000LL;
// bin (bucketed edges, NNZ int2 = 32MB) overlaid on gcn_hidden[l=1] region
// [2*SZL,3*SZL): consumed by k_bfin, long before layer-1 spmm writes gcn[1].
constexpr long long OUT_BIN  = 2*SZL;

// ---- bucketed CSR build geometry ----
#define BSHIFT 10
#define RPB 1024                                   // rows per bucket
constexpr int NBKT = (N_NODES + RPB - 1)/RPB;      // 293 buckets
#define EPB 8192                                   // edges per stage-1 block
constexpr int NB_H = (NNZ + EPB - 1)/EPB;          // 489 stage-1 blocks

#define S3_CHUNK 512
constexpr int NB_S3U = (N_USERS + S3_CHUNK - 1)/S3_CHUNK;  // 196
constexpr int NB_S3I = (N_ITEMS + S3_CHUNK - 1)/S3_CHUNK;  // 391
constexpr int NB_S3  = NB_S3U + NB_S3I;                    // 587
constexpr int UB64   = N_USERS/32;                         // 3125 user gemm blocks
constexpr int NB_GEMM= N_NODES/32;                         // 9375
constexpr int NB_SPMM= N_NODES/4;                          // 75000
constexpr int NB_RED = 64;                                 // reduce blocks (32 user + 32 item)

typedef __attribute__((ext_vector_type(8))) short short8;
typedef __attribute__((ext_vector_type(4))) float f32x4;

__device__ __forceinline__ float bf2f(u16 u){ u32 i = ((u32)u) << 16; return __builtin_bit_cast(float, i); }
__device__ __forceinline__ u16 f2bf(float f){
  u32 i = __builtin_bit_cast(u32, f);
  return (u16)((i + 0x7FFFu + ((i >> 16) & 1u)) >> 16);
}

// ---------------- GEMM body ---------------------------------------------------
// C[M x N] = A[M x K] @ B[K x N]; A row-major bf16 (AF32=false) or fp32
// converted on the fly with the same f2bf rounding (AF32=true, bit-identical).
// B fp32 staged in LDS as bf16. 32 rows/block, 4 waves. User+item merged.
// FUSE: layer epilogue h = gcn+hg; hsum += h; hbf = bf16(h); hg nontemporal.
// WRINIT (requires AF32): the (wave&1)==0 waves also emit hsum=f32(A) and
// hbf=bf16(A) while staging A -- folds the old k_init into this GEMM (each
// (row,elem) is staged by exactly one such lane), saving a second 115MB read
// of emb.
template<int K, int N, bool C32, bool FUSE, bool AF32, bool WRINIT>
__device__ __forceinline__ void gemm_body(int bid, const void* __restrict__ A0,
                                          const float* __restrict__ Bu,
                                          const float* __restrict__ Bi,
                                          void* __restrict__ Cv,
                                          const float* __restrict__ gcn0,
                                          float* __restrict__ hsum0,
                                          u16* __restrict__ hbf0,
                                          int ublocks, u32* blds){
  bool it = bid >= ublocks;
  int blk = it ? bid - ublocks : bid;
  const float* B = it ? Bi : Bu;
  size_t aoff = it ? (size_t)ublocks*32*K : 0;
  size_t co   = it ? (size_t)ublocks*32*N : 0;

  constexpr int SROW = N + 2;                 // padded u16 stride (odd dword stride)
  constexpr int PAIRS = K*N/2;
  for (int p = threadIdx.x; p < PAIRS; p += 256){
    int k = p/(N/2), c2 = p%(N/2);
    float f0 = B[2*p], f1 = B[2*p+1];
    blds[k*(SROW/2) + c2] = (u32)f2bf(f0) | ((u32)f2bf(f1)<<16);
  }
  __syncthreads();
  const u16* bl = (const u16*)blds;
  int wave = threadIdx.x>>6, lane = threadIdx.x&63, q = lane>>4, lm = lane&15;
  constexpr int NT = N/32;
  int mt = wave>>1, ntb = (wave&1)*NT;
  int r0 = blk*32;
  f32x4 acc[NT];
  #pragma unroll
  for (int nt=0; nt<NT; ++nt) acc[nt] = (f32x4){0.f,0.f,0.f,0.f};
  size_t arow = aoff + (size_t)(r0 + mt*16 + lm)*K + q*8;
  #pragma unroll
  for (int ks = 0; ks < K/32; ++ks){
    short8 a;
    if (AF32){
      const float* af = (const float*)A0 + arow + ks*32;
      float4 f0 = *(const float4*)af;
      float4 f1 = *(const float4*)(af + 4);
      a[0]=(short)f2bf(f0.x); a[1]=(short)f2bf(f0.y);
      a[2]=(short)f2bf(f0.z); a[3]=(short)f2bf(f0.w);
      a[4]=(short)f2bf(f1.x); a[5]=(short)f2bf(f1.y);
      a[6]=(short)f2bf(f1.z); a[7]=(short)f2bf(f1.w);
      if (WRINIT && (wave & 1) == 0){
        // fold k_init: hsum = emb (fp32), h_bf = bf16(emb). Each (row,elem)
        // staged by exactly one lane of waves 0/2 (mt covers rows, q+ks elems).
        *(float4*)(hsum0 + arow + ks*32)     = f0;
        *(float4*)(hsum0 + arow + ks*32 + 4) = f1;
        *(short8*)(hbf0 + arow + ks*32)      = a;
      }
    } else {
      a = *(const short8*)((const u16*)A0 + arow + ks*32);
    }
    #pragma unroll
    for (int nt = 0; nt < NT; ++nt){
      short8 b;
      #pragma unroll
      for (int j = 0; j < 8; ++j)
        b[j] = (short)bl[(ks*32 + q*8 + j)*SROW + (ntb+nt)*16 + lm];
      acc[nt] = __builtin_amdgcn_mfma_f32_16x16x32_bf16(a, b, acc[nt], 0, 0, 0);
    }
  }
  #pragma unroll
  for (int nt = 0; nt < NT; ++nt)
    #pragma unroll
    for (int r = 0; r < 4; ++r){
      int row = r0 + mt*16 + q*4 + r;       // C/D: col=lane&15, row=quad*4+reg (m89)
      int col = (ntb+nt)*16 + lm;
      size_t idx = co + (size_t)row*N + col;
      if (C32){
        float hg = acc[nt][r];
        if (FUSE){
          __builtin_nontemporal_store(hg, &((float*)Cv)[idx]);  // hg: streaming
          float hv = gcn0[idx] + hg;
          hsum0[idx] += hv;
          hbf0[idx] = f2bf(hv);
        } else {
          ((float*)Cv)[idx] = hg;
        }
      } else {
        ((u16*)Cv)[idx] = f2bf(acc[nt][r]);
      }
    }
}

template<int K, int N, bool C32, bool FUSE>
__global__ __launch_bounds__(256) void k_gemm_tall(const u16* __restrict__ A0,
                                                   const float* __restrict__ Bu,
                                                   const float* __restrict__ Bi,
                                                   void* __restrict__ Cv,
                                                   const float* __restrict__ gcn0,
                                                   float* __restrict__ hsum0,
                                                   u16* __restrict__ hbf0,
                                                   int ublocks){
  __shared__ u32 blds[K*(N+2)/2];
  gemm_body<K,N,C32,FUSE,false,false>((int)blockIdx.x, A0, Bu, Bi, Cv, gcn0, hsum0, hbf0, ublocks, blds);
}

// k_front: bucket-histogram (LDS atomics only) || hyper GEMM (emb fp32 direct,
// WRINIT emits h_bf/hsum from the A-staging -- the old init blocks are gone).
__global__ __launch_bounds__(256) void k_front(const float* __restrict__ ue,
                                               const float* __restrict__ ie,
                                               u16* __restrict__ h_bf,
                                               float* __restrict__ hsum,
                                               const int* __restrict__ rows_,
                                               int* __restrict__ cnt_bb,
                                               const float* __restrict__ user_w,
                                               const float* __restrict__ item_w,
                                               u16* __restrict__ hyper){
  __shared__ u32 shmem[64*(HYP+2)/2];     // 16.6KB; bucket hist aliases first 293 ints
  int bid = blockIdx.x;
  int tid = threadIdx.x;
  if (bid < NB_H){
    int* hist = (int*)shmem;
    for (int i = tid; i < NBKT; i += 256) hist[i] = 0;
    __syncthreads();
    #pragma unroll
    for (int it = 0; it < 8; ++it){
      int e4 = bid*EPB + it*1024 + tid*4;
      if (e4 < NNZ){
        int4 r4 = *(const int4*)(rows_ + e4);
        atomicAdd(&hist[min(max(r4.x,0),N_NODES-1)>>BSHIFT], 1);
        atomicAdd(&hist[min(max(r4.y,0),N_NODES-1)>>BSHIFT], 1);
        atomicAdd(&hist[min(max(r4.z,0),N_NODES-1)>>BSHIFT], 1);
        atomicAdd(&hist[min(max(r4.w,0),N_NODES-1)>>BSHIFT], 1);
      }
    }
    __syncthreads();
    for (int i = tid; i < NBKT; i += 256) cnt_bb[i*NB_H + bid] = hist[i];
    return;
  }
  int gb = bid - NB_H;
  const void* A0 = (gb < UB64) ? (const void*)ue
                               : (const void*)(ie - (size_t)UB64*32*64);
  gemm_body<64,HYP,false,false,true,true>(gb, A0, user_w, item_w, hyper,
                                          nullptr, hsum, h_bf, UB64, shmem);
}

// Per-bucket exclusive scan of cnt_bb over the 489 stage-1 blocks.
__global__ __launch_bounds__(256) void k_bscan2(int* __restrict__ cnt_bb,
                                                int* __restrict__ btot){
  __shared__ int sO[512], sA[512], sB[512];
  int b = blockIdx.x, tid = threadIdx.x;
  for (int i = tid; i < 512; i += 256){
    int v = (i < NB_H) ? cnt_bb[b*NB_H + i] : 0;
    sO[i] = v; sA[i] = v;
  }
  __syncthreads();
  int* cur = sA; int* nxt = sB;
  for (int off = 1; off < 512; off <<= 1){
    for (int i = tid; i < 512; i += 256)
      nxt[i] = cur[i] + ((i >= off) ? cur[i-off] : 0);
    __syncthreads();
    int* t = cur; cur = nxt; nxt = t;
  }
  for (int i = tid; i < NB_H; i += 256)
    cnt_bb[b*NB_H + i] = cur[i] - sO[i];    // exclusive
  if (tid == 0) btot[b] = cur[NB_H-1];
}

// ---------------- step3: partial tiles (no hot atomics) ----------------------
__device__ __forceinline__ void step3_body(const u16* __restrict__ Hy,
                                           const u16* __restrict__ Hm,
                                           float* __restrict__ outp, int rows, int k0,
                                           u32* __restrict__ lds){
  u32* hyl = lds;            // 32 k-rows x 128 elems, stride 130 u16 (65 u32)
  u32* hml = lds + 32*65;    // 32 k-rows x 64 elems,  stride 66 u16 (33 u32)
  const u16* hyl16 = (const u16*)hyl;
  const u16* hml16 = (const u16*)hml;
  int tid = threadIdx.x;
  int wave = tid>>6, lane = tid&63, q = lane>>4, lm = lane&15;
  f32x4 acc[2][4];
  #pragma unroll
  for (int i=0;i<2;i++)
    #pragma unroll
    for (int j=0;j<4;j++) acc[i][j] = (f32x4){0.f,0.f,0.f,0.f};
  for (int kk=0; kk<S3_CHUNK/32; ++kk){
    int kb = k0 + kk*32;
    #pragma unroll
    for (int d0=0; d0<8; ++d0){
      int d = d0*256 + tid;
      int kr = d>>6, c2 = d&63, g = kb+kr;
      hyl[kr*65 + c2] = (g < rows) ? ((const u32*)Hy)[(size_t)g*64 + c2] : 0u;
    }
    #pragma unroll
    for (int d0=0; d0<4; ++d0){
      int d = d0*256 + tid;
      int kr = d>>5, c2 = d&31, g = kb+kr;
      hml[kr*33 + c2] = (g < rows) ? ((const u32*)Hm)[(size_t)g*32 + c2] : 0u;
    }
    __syncthreads();
    short8 a[2], b[4];
    #pragma unroll
    for (int ml=0; ml<2; ++ml)
      #pragma unroll
      for (int j=0;j<8;j++)
        a[ml][j] = (short)hyl16[(q*8+j)*130 + (wave*2+ml)*16 + lm];  // A[m][k]=Hy[k][m]
    #pragma unroll
    for (int nt=0; nt<4; ++nt)
      #pragma unroll
      for (int j=0;j<8;j++)
        b[nt][j] = (short)hml16[(q*8+j)*66 + nt*16 + lm];            // B[k][n]=Hm[k][n]
    #pragma unroll
    for (int ml=0; ml<2; ++ml)
      #pragma unroll
      for (int nt=0; nt<4; ++nt)
        acc[ml][nt] = __builtin_amdgcn_mfma_f32_16x16x32_bf16(a[ml], b[nt], acc[ml][nt], 0,0,0);
    __syncthreads();
  }
  #pragma unroll
  for (int ml=0; ml<2; ++ml)
    #pragma unroll
    for (int nt=0; nt<4; ++nt)
      #pragma unroll
      for (int r=0;r<4;r++){
        int m = (wave*2+ml)*16 + q*4 + r;
        int n = nt*16 + lm;
        __builtin_nontemporal_store(acc[ml][nt][r], &outp[m*64 + n]);
      }
}

__device__ __forceinline__ void step3_dispatch(int bid, const u16* __restrict__ hyper,
                                               const u16* __restrict__ h,
                                               float* __restrict__ part, u32* lds){
  float* outp = part + (size_t)bid*8192;
  if (bid < NB_S3U)
    step3_body(hyper, h, outp, N_USERS, bid*S3_CHUNK, lds);
  else
    step3_body(hyper + (size_t)N_USERS*HYP, h + (size_t)N_USERS*D,
               outp, N_ITEMS, (bid - NB_S3U)*S3_CHUNK, lds);
}

__global__ __launch_bounds__(256) void k_step3(const u16* __restrict__ hyper,
                                               const u16* __restrict__ h,
                                               float* __restrict__ part){
  __shared__ u32 lds[32*65 + 32*33];
  step3_dispatch((int)blockIdx.x, hyper, h, part, lds);
}

// k_mid: bbin (LDS-cursor bucket scatter) || step3 layer 0 (MFMA).
// bin stores are PLAIN: each block exclusively owns ~224B runs per bucket ->
// L2 write-allocate merges ~8 edges/line (nt here caused 4x amplification, r8).
// Bucket offsets re-derived from btot via a 512-wide LDS scan (k_bbase folded).
__global__ __launch_bounds__(256) void k_mid(const int* __restrict__ rows_,
                                             const int* __restrict__ cols_,
                                             const float* __restrict__ vals_,
                                             const int* __restrict__ cnt_bb,
                                             const int* __restrict__ btot,
                                             int2* __restrict__ bin,
                                             const u16* __restrict__ hyper,
                                             const u16* __restrict__ h_bf,
                                             float* __restrict__ part){
  __shared__ u32 lds[32*65 + 32*33];      // 12.5KB; bbin state aliases the front
  int bid = blockIdx.x, tid = threadIdx.x;
  if (bid < NB_H){
    int* cur = (int*)lds;                 // [0,293): cursors
    int* scA = (int*)lds + 512;           // [512,1024): scan buf A
    int* scB = (int*)lds + 1024;          // [1024,1536): scan buf B
    for (int i = tid; i < 512; i += 256) scA[i] = (i < NBKT) ? btot[i] : 0;
    __syncthreads();
    int* c = scA; int* n = scB;
    for (int off = 1; off < 512; off <<= 1){
      for (int i = tid; i < 512; i += 256)
        n[i] = c[i] + ((i >= off) ? c[i-off] : 0);
      __syncthreads();
      int* t = c; c = n; n = t;
    }
    for (int i = tid; i < NBKT; i += 256)
      cur[i] = ((i == 0) ? 0 : c[i-1]) + cnt_bb[i*NB_H + bid];
    __syncthreads();
    #pragma unroll
    for (int it = 0; it < 8; ++it){
      int e4 = bid*EPB + it*1024 + tid*4;
      if (e4 < NNZ){
        int4 r4 = *(const int4*)(rows_ + e4);
        int4 c4 = *(const int4*)(cols_ + e4);
        float4 v4 = *(const float4*)(vals_ + e4);
        int rr[4] = {r4.x, r4.y, r4.z, r4.w};
        int cc[4] = {c4.x, c4.y, c4.z, c4.w};
        float vv[4] = {v4.x, v4.y, v4.z, v4.w};
        #pragma unroll
        for (int j = 0; j < 4; ++j){
          int r = min(max(rr[j],0), N_NODES-1);
          int cl = min(max(cc[j],0), N_NODES-1);
          int pos = atomicAdd(&cur[r >> BSHIFT], 1);
          pos = min(max(pos,0), NNZ-1);
          int pack = ((r & (RPB-1)) << 19) | cl;  // rowlocal:10b | col:19b
          bin[pos] = make_int2(pack, __float_as_int(vv[j]));  // plain: let L2 merge
        }
      }
    }
    return;
  }
  step3_dispatch(bid - NB_H, hyper, h_bf, part, lds);
}

// Finalize: per bucket, LDS row-histogram -> LDS scan -> write rowptr ->
// LDS-cursor scatter of {col,val} into the bucket's L2-resident output range.
// bin is read-once: nontemporal loads. Bucket offsets from btot scan (k_bbase
// folded): ebeg = incl[b-1], eend = incl[b].
__global__ __launch_bounds__(256) void k_bfin(const int2* __restrict__ bin,
                                              const int* __restrict__ btot,
                                              int* __restrict__ rowptr,
                                              int2* __restrict__ pair_s){
  __shared__ int s_hist[RPB];
  __shared__ int sA[RPB], sB[RPB];
  int b = blockIdx.x, tid = threadIdx.x;
  // btot scan (512-wide) using sA/sB before their row-scan use
  for (int i = tid; i < 512; i += 256) sA[i] = (i < NBKT) ? btot[i] : 0;
  __syncthreads();
  int* cur = sA; int* nxt = sB;
  for (int off = 1; off < 512; off <<= 1){
    for (int i = tid; i < 512; i += 256)
      nxt[i] = cur[i] + ((i >= off) ? cur[i-off] : 0);
    __syncthreads();
    int* t = cur; cur = nxt; nxt = t;
  }
  int ebeg = (b == 0) ? 0 : cur[b-1];
  int eend = cur[b];
  int base = ebeg;
  __syncthreads();
  for (int i = tid; i < RPB; i += 256) s_hist[i] = 0;
  __syncthreads();
  for (int e = ebeg + tid; e < eend; e += 256){
    u64 pvu = __builtin_nontemporal_load((const u64*)(bin + e));
    int pack = (int)(u32)pvu;
    atomicAdd(&s_hist[(pack >> 19) & (RPB-1)], 1);
  }
  __syncthreads();
  for (int i = tid; i < RPB; i += 256) sA[i] = s_hist[i];
  __syncthreads();
  cur = sA; nxt = sB;
  for (int off = 1; off < RPB; off <<= 1){
    for (int i = tid; i < RPB; i += 256)
      nxt[i] = cur[i] + ((i >= off) ? cur[i-off] : 0);
    __syncthreads();
    int* t = cur; cur = nxt; nxt = t;
  }
  // cur = inclusive; cursor/rowptr value = base + (inclusive - hist) = exclusive
  int r0 = b << BSHIFT;
  for (int i = tid; i < RPB; i += 256){
    int v = base + cur[i] - s_hist[i];
    nxt[i] = v;                          // nxt reused as the scatter cursor
    if (r0 + i <= N_NODES) rowptr[r0 + i] = v;
  }
  __syncthreads();
  for (int e = ebeg + tid; e < eend; e += 256){
    u64 pvu = __builtin_nontemporal_load((const u64*)(bin + e));
    int pack = (int)(u32)pvu;
    int rl = (pack >> 19) & (RPB-1);
    int c  = pack & 0x7FFFF;
    int pos = atomicAdd(&nxt[rl], 1);
    pos = min(max(pos,0), NNZ-1);
    pair_s[pos] = make_int2(c, (int)(u32)(pvu >> 32));
  }
}

// ---------------- spmm (+merged partial-tile reduce) --------------------------
// Blocks [0,NB_RED): full-range sum of step3 partials -> tmp (plain stores, no
// atomics, no pre-zero). Blocks [NB_RED,...): one wave per row. DUAL-EDGE
// gathers (round-12 proven best; oct-edge u128 regressed +13% in r14 --
// 4x VALU work + VGPR pressure for deg<=16-dominated rows): lanes 0-31
// service edge e+2j, lanes 32-63 edge e+2j+1; each lane loads u32 (2 bf16)
// at h[ce]*64 + (lane&31)*2 -> 16 edges in flight per wave, instruction count
// scales with actual degree. Epilogue combines halves via shfl_xor(32);
// lanes 0-31 store float2 (256B/row, nt). Padded lanes c=0,v=0 -> 0.
__global__ __launch_bounds__(256) void k_spmm(const int* __restrict__ rp,
                                              const int2* __restrict__ ps,
                                              const u16* __restrict__ h,
                                              float* __restrict__ gout,
                                              const float* __restrict__ part,
                                              float* __restrict__ tmp){
  int bid = blockIdx.x;
  if (bid < NB_RED){
    int j = (bid & 31)*256 + threadIdx.x;
    float s = 0.f;
    if (bid < 32){
      for (int b = 0; b < NB_S3U; ++b) s += part[(size_t)b*8192 + j];
      tmp[j] = s;
    } else {
      for (int b = NB_S3U; b < NB_S3; ++b) s += part[(size_t)b*8192 + j];
      tmp[HYP*D + j] = s;
    }
    return;
  }
  int r = (bid - NB_RED)*4 + (threadIdx.x>>6);
  int lane = threadIdx.x & 63;
  int half = lane >> 5;          // 0: even edges, 1: odd edges
  int lp   = lane & 31;          // element-pair index within the row
  int beg = rp[r], end = rp[r+1];
  float acc0 = 0.f, acc1 = 0.f;
  for (int base = beg; base < end; base += 64){
    int c = 0; float v = 0.f;
    if (base + lane < end){
      u64 pvu = __builtin_nontemporal_load((const u64*)(ps + base + lane));
      c = (int)(u32)pvu; v = __int_as_float((int)(u32)(pvu >> 32));
    }
    int n = end - base; if (n > 64) n = 64;
    for (int e = 0; e < n; e += 16){
      int ce[8]; float ve[8]; u32 hw[8];
      #pragma unroll
      for (int j = 0; j < 8; ++j){
        ce[j] = __shfl(c, e + 2*j + half);
        ve[j] = __shfl(v, e + 2*j + half);
      }
      #pragma unroll
      for (int j = 0; j < 8; ++j)
        hw[j] = *(const u32*)(h + (size_t)ce[j]*64 + lp*2);  // 8 gathers, 2 edges each
      #pragma unroll
      for (int j = 0; j < 8; ++j){
        acc0 += ve[j] * bf2f((u16)(hw[j] & 0xFFFFu));
        acc1 += ve[j] * bf2f((u16)(hw[j] >> 16));
      }
    }
  }
  acc0 += __shfl_xor(acc0, 32);
  acc1 += __shfl_xor(acc1, 32);
  if (half == 0){
    u64 w = (u64)__builtin_bit_cast(u32, acc0) | ((u64)__builtin_bit_cast(u32, acc1) << 32);
    __builtin_nontemporal_store(w, (u64*)(gout + (size_t)r*64 + lp*2));
  }
}

extern "C" void kernel_launch(void* const* d_in, const int* in_sizes, int n_in,
                              void* d_out, int out_size, void* d_ws, size_t ws_size,
                              hipStream_t stream) {
  const float* user_emb = (const float*)d_in[0];
  const float* item_emb = (const float*)d_in[1];
  const float* user_w   = (const float*)d_in[2];
  const float* item_w   = (const float*)d_in[3];
  const float* adj_vals = (const float*)d_in[4];
  const int* adj_rows = (const int*)d_in[5];
  const int* adj_cols = (const int*)d_in[6];
  float* out = (float*)d_out;

  // ws (~117 MB): hyper 76.8M + h_bf 38.4M + rowptr 1.2M + cnt_bb 0.6M + misc
  char* w = (char*)d_ws;
  auto alloc = [&](size_t b){ void* p = (void*)w; w += (b + 255) & ~(size_t)255; return p; };
  u16*   hyper  = (u16*)  alloc((size_t)N_NODES*HYP*2);
  u16*   h_bf   = (u16*)  alloc((size_t)N_NODES*D*2);
  int*   rowptr = (int*)  alloc((size_t)(N_NODES+1)*4);
  int*   cnt_bb = (int*)  alloc((size_t)NBKT*NB_H*4);
  int*   btot   = (int*)  alloc((size_t)NBKT*4);
  float* tmp_u  = (float*)alloc((size_t)HYP*D*4);  // tmp_i = tmp_u + HYP*D
  float* tmp_i  = (float*)alloc((size_t)HYP*D*4);
  (void)tmp_i;

  // Overlays on out (regions free until noted launch):
  int2*  pair_s = (int2*)(out + OUT_PAIR);         // hgnn[1]: free until gemm1
  float* part   = out + OUT_PART;                  // after pair_s, same region
  int2*  bin    = (int2*)(out + OUT_BIN);          // gcn[1]: free until l1 spmm
  float* hsum   = out;                             // fp32 hidden-sum accumulator

  // 1. bucket-hist (LDS atomics) || hyper-GEMM (emb fp32 direct, WRINIT emits
  //    h_bf + hsum from the A-staging; the old init pass is deleted)
  k_front<<<NB_H + NB_GEMM, 256, 0, stream>>>(
      user_emb, item_emb, h_bf, hsum, adj_rows, cnt_bb, user_w, item_w, hyper);

  // 2. scan block-bucket matrix (bucket offsets derived in consumers)
  k_bscan2<<<NBKT, 256, 0, stream>>>(cnt_bb, btot);

  // 3. bin edges by bucket || step3 layer 0
  k_mid<<<NB_H + NB_S3, 256, 0, stream>>>(adj_rows, adj_cols, adj_vals,
                                          cnt_bb, btot, bin, hyper, h_bf, part);

  // 4. finalize CSR (rowptr + row-sorted pairs, L2-resident per-bucket scatter)
  k_bfin<<<NBKT, 256, 0, stream>>>(bin, btot, rowptr, pair_s);

  // 5. layer-0 spmm || reduce(l0 partials -> tmp)
  k_spmm<<<NB_RED + NB_SPMM, 256, 0, stream>>>(rowptr, pair_s, h_bf,
                                               out + OUT_GCN0, part, tmp_u);
  // 6. layer-0 fused hg GEMM + epilogue
  k_gemm_tall<128,64,true,true><<<NB_GEMM, 256, 0, stream>>>(
      hyper, tmp_u, tmp_u + HYP*D, out + OUT_HG0, out + OUT_GCN0, hsum, h_bf, UB64);

  // 7. step3 layer 1 (h_bf updated by gemm0)
  k_step3<<<NB_S3, 256, 0, stream>>>(hyper, h_bf, part);
  // 8. layer-1 spmm || reduce
  k_spmm<<<NB_RED + NB_SPMM, 256, 0, stream>>>(rowptr, pair_s, h_bf,
                                               out + OUT_GCN0 + SZL, part, tmp_u);
  // 9. layer-1 fused hg GEMM + epilogue
  k_gemm_tall<128,64,true,true><<<NB_GEMM, 256, 0, stream>>>(
      hyper, tmp_u, tmp_u + HYP*D, out + OUT_HG0 + SZL, out + OUT_GCN0 + SZL,
      hsum, h_bf, UB64);
}